// Round 17
// baseline (202.254 us; speedup 1.0000x reference)
//
#include <hip/hip_runtime.h>
#include <stdint.h>

#define MM 16384
#define KK 2048
#define NN 2048
#define GG 64
#define EPSV 1e-5f
#define NT 32           // K tiles of 64

typedef short short8 __attribute__((ext_vector_type(8)));
typedef float floatx4 __attribute__((ext_vector_type(4)));

__device__ __forceinline__ uint16_t f2bf(float f) {
  uint32_t u = __float_as_uint(f);
  u = (u + 0x7fffu + ((u >> 16) & 1u)) >> 16;
  return (uint16_t)u;
}

// Single fused converter: grid-stride over the concatenated [x | W] f32
// range -> concatenated [xbf | wbf] bf16 workspace (saves one dispatch).
__global__ void cvt_f32_to_bf16(const float* __restrict__ src,
                                uint16_t* __restrict__ dst, int n4) {
  int stride = gridDim.x * blockDim.x;
  for (int i = blockIdx.x * blockDim.x + threadIdx.x; i < n4; i += stride) {
    floatx4 v = __builtin_nontemporal_load(
        reinterpret_cast<const floatx4*>(src) + i);
    ushort4 o;
    o.x = f2bf(v.x); o.y = f2bf(v.y); o.z = f2bf(v.z); o.w = f2bf(v.w);
    reinterpret_cast<ushort4*>(dst)[i] = o;
  }
}

__global__ void cvt2_f32_to_bf16(const float* __restrict__ s0, int n0,
                                 const float* __restrict__ s1, int n1,
                                 uint16_t* __restrict__ dst) {
  int stride = gridDim.x * blockDim.x;
  int total = n0 + n1;   // in float4 units
  for (int i = blockIdx.x * blockDim.x + threadIdx.x; i < total; i += stride) {
    const floatx4* p = (i < n0) ? (reinterpret_cast<const floatx4*>(s0) + i)
                                : (reinterpret_cast<const floatx4*>(s1) + (i - n0));
    floatx4 v = __builtin_nontemporal_load(p);
    ushort4 o;
    o.x = f2bf(v.x); o.y = f2bf(v.y); o.z = f2bf(v.z); o.w = f2bf(v.w);
    reinterpret_cast<ushort4*>(dst)[i] = o;
  }
}

__device__ __forceinline__ void gload_lds16(const void* g, void* l) {
  __builtin_amdgcn_global_load_lds(
      (const __attribute__((address_space(1))) void*)g,
      (__attribute__((address_space(3))) void*)l, 16, 0, 0);
}

// DPP 16-lane row reduction (pure VALU, lanes [lhi*16..lhi*16+15] = DPP row).
#define ROR_ADD(v, n)                                                      \
  v += __int_as_float(__builtin_amdgcn_update_dpp(                         \
      0, __float_as_int(v), 0x120 + (n), 0xF, 0xF, true))
#define ROW_REDUCE(v) { ROR_ADD(v, 1); ROR_ADD(v, 2); ROR_ADD(v, 4); ROR_ADD(v, 8); }

// r17 = r15 config (best total 199.7us: NT cvt loads + NT epilogue stores —
// NT stores cost +5us inside the GEMM dispatch but keep the 128MB output
// from evicting L2/L3 staging lines, net-positive across the replay loop)
// + fused single-launch converter (one dispatch gap removed).
// Search summary (r2-r16): 16x16x32 frags + 256x256 tile + 1-tile-ahead DMA
// staging + single barrier/K-tile is the source-level local optimum;
// schedule/locality/demand levers all null or negative on this shape.
__global__ __launch_bounds__(512, 2)
void gemm_gn_silu_ol(const uint16_t* __restrict__ xb,  // M x K bf16
                     const uint16_t* __restrict__ wb,  // N x K bf16
                     const float* __restrict__ bias,   // N
                     const float* __restrict__ gnw,    // G
                     const float* __restrict__ gnb,    // G
                     const float* __restrict__ mw,     // N
                     float* __restrict__ out) {        // M x N f32
  extern __shared__ char lds[];   // 131072 bytes

  int bid = blockIdx.x;
  // XCD chunk swizzle: 512 blocks, 8 XCDs, 64 consecutive tiles per XCD.
  int wgs = ((bid & 7) << 6) | (bid >> 3);
  int tm = wgs >> 3;          // 0..63  (M tiles)
  int tn = wgs & 7;           // 0..7   (N tiles)
  int row0 = tm * 256;
  int col0 = tn * 256;

  int t = threadIdx.x;
  int lane = t & 63;
  int wid = t >> 6;
  int wm = wid >> 2, wn = wid & 3;   // 2x4 wave grid
  int llo = lane & 15, lhi = lane >> 4;
  int sw = (llo & 7) << 4;

  const char* xgb = (const char*)xb + (size_t)row0 * (KK * 2);
  const char* wgb = (const char*)wb + (size_t)col0 * (KK * 2);

  // staging addresses: LDS dest linear; source column pre-swizzled (rule #21).
  int o16 = t * 16;                 // 0..8176
  int srow = o16 >> 7;              // 0..63
  int spb = (o16 & 127) ^ ((srow & 7) << 4);
  const char* gaSrc = xgb + (size_t)srow * (KK * 2) + spb;
  const char* gbSrc = wgb + (size_t)srow * (KK * 2) + spb;

  auto stageA = [&](int buf, int h, int kt) {
    if (kt < NT) {
      const char* s = gaSrc + (size_t)h * (128 * KK * 2) + (size_t)kt * 128;
      char* d = lds + buf * 65536 + h * 16384 + o16;
      gload_lds16(s, d);
      gload_lds16(s + 64 * (KK * 2), d + 8192);
    }
  };
  auto stageB = [&](int buf, int h, int kt) {
    if (kt < NT) {
      const char* s = gbSrc + (size_t)h * (128 * KK * 2) + (size_t)kt * 128;
      char* d = lds + buf * 65536 + 32768 + h * 16384 + o16;
      gload_lds16(s, d);
      gload_lds16(s + 64 * (KK * 2), d + 8192);
    }
  };

  // Precomputed LDS byte offsets: row = (wm*128+llo)+mh*64+mi2*16; (row&7)
  // == llo&7 for all frags -> swizzled k-offset fragment-invariant, fragment
  // selector is a compile-time immediate.
  uint32_t aOff[2][2], bOff[2][2];
  #pragma unroll
  for (int buf = 0; buf < 2; ++buf)
    #pragma unroll
    for (int kk = 0; kk < 2; ++kk) {
      uint32_t ko = (uint32_t)((kk * 64 + lhi * 16) ^ sw);
      aOff[buf][kk] = buf * 65536u + (uint32_t)(wm * 128 + llo) * 128u + ko;
      bOff[buf][kk] = buf * 65536u + 32768u + (uint32_t)(wn * 64 + llo) * 128u + ko;
    }

  short8 a[4][2], ah[4][2], blo[2][2], bhi[2][2];
  floatx4 acc[8][4] = {};

#define RDA(buf, mh, aa)                                                   \
  {                                                                        \
    _Pragma("unroll") for (int kk = 0; kk < 2; ++kk)                       \
        _Pragma("unroll") for (int mi2 = 0; mi2 < 4; ++mi2)                \
            aa[mi2][kk] = *(const short8*)(lds + aOff[buf][kk] +           \
                                           (mh)*8192 + mi2 * 2048);        \
  }
#define RDB(buf, nh, bq)                                                   \
  {                                                                        \
    _Pragma("unroll") for (int kk = 0; kk < 2; ++kk)                       \
        _Pragma("unroll") for (int ni2 = 0; ni2 < 2; ++ni2)                \
            bq[ni2][kk] = *(const short8*)(lds + bOff[buf][kk] +           \
                                           (nh)*4096 + ni2 * 2048);        \
  }
  // kk OUTER: 8 independent MFMAs between accumulator reuse.
#define MFMAQ(mh, nh, bq, aa)                                              \
  {                                                                        \
    _Pragma("unroll") for (int kk = 0; kk < 2; ++kk)                       \
        _Pragma("unroll") for (int mi2 = 0; mi2 < 4; ++mi2)                \
            _Pragma("unroll") for (int ni2 = 0; ni2 < 2; ++ni2)            \
                acc[(mh)*4 + mi2][(nh)*2 + ni2] =                          \
                    __builtin_amdgcn_mfma_f32_16x16x32_bf16(               \
                        aa[mi2][kk], bq[ni2][kk],                          \
                        acc[(mh)*4 + mi2][(nh)*2 + ni2], 0, 0, 0);         \
  }

  // Prologue: stage tile 0 into buf 0, drain, sync.
  stageA(0, 0, 0); stageA(0, 1, 0);
  stageB(0, 0, 0); stageB(0, 1, 0);
  __syncthreads();   // implicit vmcnt(0) drain: tile0 resident

  bool odd = (wid & 1) != 0;   // wave-uniform

  #pragma unroll 1
  for (int kt = 0; kt < NT; ++kt) {
    int buf = kt & 1;
    // stage next tile into the other buffer (8 gloads, 1 tile ahead)
    stageA(buf ^ 1, 0, kt + 1); stageA(buf ^ 1, 1, kt + 1);
    stageB(buf ^ 1, 0, kt + 1); stageB(buf ^ 1, 1, kt + 1);
    __builtin_amdgcn_s_setprio(1);
    if (!odd) {
      // even waves: quadrants (0,0),(0,1),(1,1),(1,0)
      if (buf == 0) { RDA(0, 0, a); RDB(0, 0, blo); RDB(0, 1, bhi); RDA(0, 1, ah); }
      else          { RDA(1, 0, a); RDB(1, 0, blo); RDB(1, 1, bhi); RDA(1, 1, ah); }
      MFMAQ(0, 0, blo, a);
      MFMAQ(0, 1, bhi, a);
      MFMAQ(1, 1, bhi, ah);
      MFMAQ(1, 0, blo, ah);
    } else {
      // odd waves: rotated by 2 -> (1,1),(1,0),(0,0),(0,1); read ah/bhi first
      if (buf == 0) { RDA(0, 1, ah); RDB(0, 1, bhi); RDB(0, 0, blo); RDA(0, 0, a); }
      else          { RDA(1, 1, ah); RDB(1, 1, bhi); RDB(1, 0, blo); RDA(1, 0, a); }
      MFMAQ(1, 1, bhi, ah);
      MFMAQ(1, 0, blo, ah);
      MFMAQ(0, 0, blo, a);
      MFMAQ(0, 1, bhi, a);
    }
    __builtin_amdgcn_s_setprio(0);
    __syncthreads();   // one barrier per K-tile; drains stage loads
  }

  // ---- fused epilogue: bias + GroupNorm(32) + SiLU * mw * SiLU ----
  // C/D frag: col = cb + ni*16 + llo ; row = rb + mi*16 + lhi*4 + j
  // Reduce groups = DPP rows (lanes lhi*16..lhi*16+15): pure-VALU row_ror.
  int cb = col0 + wn * 64;   // 2 groups of 32 per wave
  int rb = row0 + wm * 128;

  float bias_v[4], mw_v[4];
  #pragma unroll
  for (int ni = 0; ni < 4; ++ni) {
    int c = cb + ni * 16 + llo;
    bias_v[ni] = bias[c];
    mw_v[ni] = mw[c];
  }
  #pragma unroll
  for (int mi = 0; mi < 8; ++mi)
    #pragma unroll
    for (int ni = 0; ni < 4; ++ni)
      #pragma unroll
      for (int j = 0; j < 4; ++j)
        acc[mi][ni][j] += bias_v[ni];

  #pragma unroll
  for (int mi = 0; mi < 8; ++mi) {
    #pragma unroll
    for (int gp = 0; gp < 2; ++gp) {
      int g = (cb >> 5) + gp;
      float gw = gnw[g], gb = gnb[g];
      float s[4], ss[4];
      #pragma unroll
      for (int j = 0; j < 4; ++j) {
        float a0 = acc[mi][2 * gp][j];
        float a1 = acc[mi][2 * gp + 1][j];
        s[j] = a0 + a1;
        ss[j] = a0 * a0 + a1 * a1;
      }
      #pragma unroll
      for (int j = 0; j < 4; ++j) {
        ROW_REDUCE(s[j]);
        ROW_REDUCE(ss[j]);
      }
      #pragma unroll
      for (int j = 0; j < 4; ++j) {
        float mean = s[j] * (1.0f / 32.0f);
        float var  = ss[j] * (1.0f / 32.0f) - mean * mean;
        float rstd = rsqrtf(var + EPSV);
        int r = rb + mi * 16 + lhi * 4 + j;
        #pragma unroll
        for (int nn = 0; nn < 2; ++nn) {
          int ni = 2 * gp + nn;
          float v = (acc[mi][ni][j] - mean) * rstd * gw + gb;
          v = v / (1.0f + __expf(-v));   // SiLU
          v = v * mw_v[ni];
          v = v / (1.0f + __expf(-v));   // SiLU
          __builtin_nontemporal_store(
              v, out + (size_t)r * NN + (cb + ni * 16 + llo));
        }
      }
    }
  }
}

// ---------------- naive f32 fallback (only if ws too small) ----------------
__global__ void naive_gemm(const float* __restrict__ x, const float* __restrict__ w,
                           const float* __restrict__ bias, float* __restrict__ out) {
  size_t idx = (size_t)blockIdx.x * 256 + threadIdx.x;
  int m = (int)(idx >> 11);
  int n = (int)(idx & 2047);
  const float* xr = x + (size_t)m * KK;
  const float* wr = w + (size_t)n * KK;
  float s = bias[n];
  for (int k = 0; k < KK; k += 4)
    s += xr[k] * wr[k] + xr[k+1] * wr[k+1] + xr[k+2] * wr[k+2] + xr[k+3] * wr[k+3];
  out[idx] = s;
}

__global__ void naive_post(float* __restrict__ out, const float* __restrict__ gnw,
                           const float* __restrict__ gnb, const float* __restrict__ mw) {
  size_t idx = (size_t)blockIdx.x * 256 + threadIdx.x;  // M*G
  int m = (int)(idx >> 6);
  int g = (int)(idx & 63);
  float* p = out + (size_t)m * NN + g * 32;
  float s = 0.f, ss = 0.f;
  for (int j = 0; j < 32; ++j) { float v = p[j]; s += v; ss += v * v; }
  float mean = s * (1.0f / 32.0f);
  float var  = ss * (1.0f / 32.0f) - mean * mean;
  float rstd = rsqrtf(var + EPSV);
  float gw = gnw[g], gb = gnb[g];
  for (int j = 0; j < 32; ++j) {
    float v = (p[j] - mean) * rstd * gw + gb;
    v = v / (1.0f + __expf(-v));
    v = v * mw[g * 32 + j];
    v = v / (1.0f + __expf(-v));
    p[j] = v;
  }
}

extern "C" void kernel_launch(void* const* d_in, const int* in_sizes, int n_in,
                              void* d_out, int out_size, void* d_ws, size_t ws_size,
                              hipStream_t stream) {
  const float* x    = (const float*)d_in[0];
  const float* wgt  = (const float*)d_in[1];
  const float* bias = (const float*)d_in[2];
  const float* gnw  = (const float*)d_in[3];
  const float* gnb  = (const float*)d_in[4];
  const float* mwp  = (const float*)d_in[5];
  float* out = (float*)d_out;

  size_t need = ((size_t)MM * KK + (size_t)NN * KK) * 2;
  if (ws_size >= need) {
    uint16_t* xbf = (uint16_t*)d_ws;
    uint16_t* wbf = xbf + (size_t)MM * KK;
    // single fused conversion launch: [x | W] -> [xbf | wbf]
    cvt2_f32_to_bf16<<<2560, 256, 0, stream>>>(x, (MM * KK) / 4,
                                               wgt, (NN * KK) / 4, xbf);
    (void)hipFuncSetAttribute((const void*)gemm_gn_silu_ol,
                              hipFuncAttributeMaxDynamicSharedMemorySize, 131072);
    gemm_gn_silu_ol<<<512, 512, 131072, stream>>>(xbf, wbf, bias, gnw, gnb, mwp, out);
  } else {
    naive_gemm<<<(MM * (size_t)NN) / 256, 256, 0, stream>>>(x, wgt, bias, out);
    naive_post<<<(MM * GG) / 256, 256, 0, stream>>>(out, gnw, gnb, mwp);
  }
}

// Round 18
// 199.525 us; speedup vs baseline: 1.0137x; 1.0137x over previous
//
#include <hip/hip_runtime.h>
#include <stdint.h>

#define MM 16384
#define KK 2048
#define NN 2048
#define GG 64
#define EPSV 1e-5f
#define NT 32           // K tiles of 64

typedef short short8 __attribute__((ext_vector_type(8)));
typedef float floatx4 __attribute__((ext_vector_type(4)));

__device__ __forceinline__ uint16_t f2bf(float f) {
  uint32_t u = __float_as_uint(f);
  u = (u + 0x7fffu + ((u >> 16) & 1u)) >> 16;
  return (uint16_t)u;
}

__global__ void cvt_f32_to_bf16(const float* __restrict__ src,
                                uint16_t* __restrict__ dst, int n4) {
  int stride = gridDim.x * blockDim.x;
  for (int i = blockIdx.x * blockDim.x + threadIdx.x; i < n4; i += stride) {
    floatx4 v = __builtin_nontemporal_load(
        reinterpret_cast<const floatx4*>(src) + i);
    ushort4 o;
    o.x = f2bf(v.x); o.y = f2bf(v.y); o.z = f2bf(v.z); o.w = f2bf(v.w);
    reinterpret_cast<ushort4*>(dst)[i] = o;
  }
}

__device__ __forceinline__ void gload_lds16(const void* g, void* l) {
  __builtin_amdgcn_global_load_lds(
      (const __attribute__((address_space(1))) void*)g,
      (__attribute__((address_space(3))) void*)l, 16, 0, 0);
}

// DPP 16-lane row reduction (pure VALU, lanes [lhi*16..lhi*16+15] = DPP row).
#define ROR_ADD(v, n)                                                      \
  v += __int_as_float(__builtin_amdgcn_update_dpp(                         \
      0, __float_as_int(v), 0x120 + (n), 0xF, 0xF, true))
#define ROW_REDUCE(v) { ROR_ADD(v, 1); ROR_ADD(v, 2); ROR_ADD(v, 4); ROR_ADD(v, 8); }

// FINAL (r18 = r15, best measured total 199.7us):
//   cvt: 2 launches, nontemporal f32x4 loads (read-once source) ~19us.
//   GEMM: 256x256 tile, 8 waves 2Mx4N, BK=64, 16x16x32 bf16 MFMA,
//     1-tile-ahead global_load_lds staging (dest linear, source
//     pre-swizzled, rule #21), XOR-swizzled ds_read_b128 (0 bank
//     conflicts), wave-parity quadrant rotation, single barrier/K-tile,
//     fused bias+GroupNorm(32)+SiLU*mw*SiLU epilogue with DPP row_ror
//     reductions and nontemporal stores (write-once output; +5us inside
//     dispatch, net-positive across the replay pipeline via L2 retention).
// Search record (r1-r17): 13 structural alternatives falsified — 8-phase
// counted-vmcnt, raw-asm barriers, read-ahead register pipelines, 3-buffer
// rotation, XCD locality remaps, B-direct-to-register, 32x32 fragments,
// fused A-conversion. All bound by LDS-pipe/matrix-pipe demand
// serialization (~2500cyc MFMA + ~2800cyc LDS per K-tile per CU) that
// source-level scheduling could not overlap on this K=2048 shape.
__global__ __launch_bounds__(512, 2)
void gemm_gn_silu_ol(const uint16_t* __restrict__ xb,  // M x K bf16
                     const uint16_t* __restrict__ wb,  // N x K bf16
                     const float* __restrict__ bias,   // N
                     const float* __restrict__ gnw,    // G
                     const float* __restrict__ gnb,    // G
                     const float* __restrict__ mw,     // N
                     float* __restrict__ out) {        // M x N f32
  extern __shared__ char lds[];   // 131072 bytes

  int bid = blockIdx.x;
  // XCD chunk swizzle: 512 blocks, 8 XCDs, 64 consecutive tiles per XCD.
  int wgs = ((bid & 7) << 6) | (bid >> 3);
  int tm = wgs >> 3;          // 0..63  (M tiles)
  int tn = wgs & 7;           // 0..7   (N tiles)
  int row0 = tm * 256;
  int col0 = tn * 256;

  int t = threadIdx.x;
  int lane = t & 63;
  int wid = t >> 6;
  int wm = wid >> 2, wn = wid & 3;   // 2x4 wave grid
  int llo = lane & 15, lhi = lane >> 4;
  int sw = (llo & 7) << 4;

  const char* xgb = (const char*)xb + (size_t)row0 * (KK * 2);
  const char* wgb = (const char*)wb + (size_t)col0 * (KK * 2);

  // staging addresses: LDS dest linear; source column pre-swizzled (rule #21).
  int o16 = t * 16;                 // 0..8176
  int srow = o16 >> 7;              // 0..63
  int spb = (o16 & 127) ^ ((srow & 7) << 4);
  const char* gaSrc = xgb + (size_t)srow * (KK * 2) + spb;
  const char* gbSrc = wgb + (size_t)srow * (KK * 2) + spb;

  auto stageA = [&](int buf, int h, int kt) {
    if (kt < NT) {
      const char* s = gaSrc + (size_t)h * (128 * KK * 2) + (size_t)kt * 128;
      char* d = lds + buf * 65536 + h * 16384 + o16;
      gload_lds16(s, d);
      gload_lds16(s + 64 * (KK * 2), d + 8192);
    }
  };
  auto stageB = [&](int buf, int h, int kt) {
    if (kt < NT) {
      const char* s = gbSrc + (size_t)h * (128 * KK * 2) + (size_t)kt * 128;
      char* d = lds + buf * 65536 + 32768 + h * 16384 + o16;
      gload_lds16(s, d);
      gload_lds16(s + 64 * (KK * 2), d + 8192);
    }
  };

  // Precomputed LDS byte offsets: row = (wm*128+llo)+mh*64+mi2*16; (row&7)
  // == llo&7 for all frags -> swizzled k-offset fragment-invariant, fragment
  // selector is a compile-time immediate.
  uint32_t aOff[2][2], bOff[2][2];
  #pragma unroll
  for (int buf = 0; buf < 2; ++buf)
    #pragma unroll
    for (int kk = 0; kk < 2; ++kk) {
      uint32_t ko = (uint32_t)((kk * 64 + lhi * 16) ^ sw);
      aOff[buf][kk] = buf * 65536u + (uint32_t)(wm * 128 + llo) * 128u + ko;
      bOff[buf][kk] = buf * 65536u + 32768u + (uint32_t)(wn * 64 + llo) * 128u + ko;
    }

  short8 a[4][2], ah[4][2], blo[2][2], bhi[2][2];
  floatx4 acc[8][4] = {};

#define RDA(buf, mh, aa)                                                   \
  {                                                                        \
    _Pragma("unroll") for (int kk = 0; kk < 2; ++kk)                       \
        _Pragma("unroll") for (int mi2 = 0; mi2 < 4; ++mi2)                \
            aa[mi2][kk] = *(const short8*)(lds + aOff[buf][kk] +           \
                                           (mh)*8192 + mi2 * 2048);        \
  }
#define RDB(buf, nh, bq)                                                   \
  {                                                                        \
    _Pragma("unroll") for (int kk = 0; kk < 2; ++kk)                       \
        _Pragma("unroll") for (int ni2 = 0; ni2 < 2; ++ni2)                \
            bq[ni2][kk] = *(const short8*)(lds + bOff[buf][kk] +           \
                                           (nh)*4096 + ni2 * 2048);        \
  }
  // kk OUTER: 8 independent MFMAs between accumulator reuse.
#define MFMAQ(mh, nh, bq, aa)                                              \
  {                                                                        \
    _Pragma("unroll") for (int kk = 0; kk < 2; ++kk)                       \
        _Pragma("unroll") for (int mi2 = 0; mi2 < 4; ++mi2)                \
            _Pragma("unroll") for (int ni2 = 0; ni2 < 2; ++ni2)            \
                acc[(mh)*4 + mi2][(nh)*2 + ni2] =                          \
                    __builtin_amdgcn_mfma_f32_16x16x32_bf16(               \
                        aa[mi2][kk], bq[ni2][kk],                          \
                        acc[(mh)*4 + mi2][(nh)*2 + ni2], 0, 0, 0);         \
  }

  // Prologue: stage tile 0 into buf 0, drain, sync.
  stageA(0, 0, 0); stageA(0, 1, 0);
  stageB(0, 0, 0); stageB(0, 1, 0);
  __syncthreads();   // implicit vmcnt(0) drain: tile0 resident

  bool odd = (wid & 1) != 0;   // wave-uniform

  #pragma unroll 1
  for (int kt = 0; kt < NT; ++kt) {
    int buf = kt & 1;
    // stage next tile into the other buffer (8 gloads, 1 tile ahead)
    stageA(buf ^ 1, 0, kt + 1); stageA(buf ^ 1, 1, kt + 1);
    stageB(buf ^ 1, 0, kt + 1); stageB(buf ^ 1, 1, kt + 1);
    __builtin_amdgcn_s_setprio(1);
    if (!odd) {
      // even waves: quadrants (0,0),(0,1),(1,1),(1,0)
      if (buf == 0) { RDA(0, 0, a); RDB(0, 0, blo); RDB(0, 1, bhi); RDA(0, 1, ah); }
      else          { RDA(1, 0, a); RDB(1, 0, blo); RDB(1, 1, bhi); RDA(1, 1, ah); }
      MFMAQ(0, 0, blo, a);
      MFMAQ(0, 1, bhi, a);
      MFMAQ(1, 1, bhi, ah);
      MFMAQ(1, 0, blo, ah);
    } else {
      // odd waves: rotated by 2 -> (1,1),(1,0),(0,0),(0,1); read ah/bhi first
      if (buf == 0) { RDA(0, 1, ah); RDB(0, 1, bhi); RDB(0, 0, blo); RDA(0, 0, a); }
      else          { RDA(1, 1, ah); RDB(1, 1, bhi); RDB(1, 0, blo); RDA(1, 0, a); }
      MFMAQ(1, 1, bhi, ah);
      MFMAQ(1, 0, blo, ah);
      MFMAQ(0, 0, blo, a);
      MFMAQ(0, 1, bhi, a);
    }
    __builtin_amdgcn_s_setprio(0);
    __syncthreads();   // one barrier per K-tile; drains stage loads
  }

  // ---- fused epilogue: bias + GroupNorm(32) + SiLU * mw * SiLU ----
  // C/D frag: col = cb + ni*16 + llo ; row = rb + mi*16 + lhi*4 + j
  // Reduce groups = DPP rows (lanes lhi*16..lhi*16+15): pure-VALU row_ror.
  int cb = col0 + wn * 64;   // 2 groups of 32 per wave
  int rb = row0 + wm * 128;

  float bias_v[4], mw_v[4];
  #pragma unroll
  for (int ni = 0; ni < 4; ++ni) {
    int c = cb + ni * 16 + llo;
    bias_v[ni] = bias[c];
    mw_v[ni] = mw[c];
  }
  #pragma unroll
  for (int mi = 0; mi < 8; ++mi)
    #pragma unroll
    for (int ni = 0; ni < 4; ++ni)
      #pragma unroll
      for (int j = 0; j < 4; ++j)
        acc[mi][ni][j] += bias_v[ni];

  #pragma unroll
  for (int mi = 0; mi < 8; ++mi) {
    #pragma unroll
    for (int gp = 0; gp < 2; ++gp) {
      int g = (cb >> 5) + gp;
      float gw = gnw[g], gb = gnb[g];
      float s[4], ss[4];
      #pragma unroll
      for (int j = 0; j < 4; ++j) {
        float a0 = acc[mi][2 * gp][j];
        float a1 = acc[mi][2 * gp + 1][j];
        s[j] = a0 + a1;
        ss[j] = a0 * a0 + a1 * a1;
      }
      #pragma unroll
      for (int j = 0; j < 4; ++j) {
        ROW_REDUCE(s[j]);
        ROW_REDUCE(ss[j]);
      }
      #pragma unroll
      for (int j = 0; j < 4; ++j) {
        float mean = s[j] * (1.0f / 32.0f);
        float var  = ss[j] * (1.0f / 32.0f) - mean * mean;
        float rstd = rsqrtf(var + EPSV);
        int r = rb + mi * 16 + lhi * 4 + j;
        #pragma unroll
        for (int nn = 0; nn < 2; ++nn) {
          int ni = 2 * gp + nn;
          float v = (acc[mi][ni][j] - mean) * rstd * gw + gb;
          v = v / (1.0f + __expf(-v));   // SiLU
          v = v * mw_v[ni];
          v = v / (1.0f + __expf(-v));   // SiLU
          __builtin_nontemporal_store(
              v, out + (size_t)r * NN + (cb + ni * 16 + llo));
        }
      }
    }
  }
}

// ---------------- naive f32 fallback (only if ws too small) ----------------
__global__ void naive_gemm(const float* __restrict__ x, const float* __restrict__ w,
                           const float* __restrict__ bias, float* __restrict__ out) {
  size_t idx = (size_t)blockIdx.x * 256 + threadIdx.x;
  int m = (int)(idx >> 11);
  int n = (int)(idx & 2047);
  const float* xr = x + (size_t)m * KK;
  const float* wr = w + (size_t)n * KK;
  float s = bias[n];
  for (int k = 0; k < KK; k += 4)
    s += xr[k] * wr[k] + xr[k+1] * wr[k+1] + xr[k+2] * wr[k+2] + xr[k+3] * wr[k+3];
  out[idx] = s;
}

__global__ void naive_post(float* __restrict__ out, const float* __restrict__ gnw,
                           const float* __restrict__ gnb, const float* __restrict__ mw) {
  size_t idx = (size_t)blockIdx.x * 256 + threadIdx.x;  // M*G
  int m = (int)(idx >> 6);
  int g = (int)(idx & 63);
  float* p = out + (size_t)m * NN + g * 32;
  float s = 0.f, ss = 0.f;
  for (int j = 0; j < 32; ++j) { float v = p[j]; s += v; ss += v * v; }
  float mean = s * (1.0f / 32.0f);
  float var  = ss * (1.0f / 32.0f) - mean * mean;
  float rstd = rsqrtf(var + EPSV);
  float gw = gnw[g], gb = gnb[g];
  for (int j = 0; j < 32; ++j) {
    float v = (p[j] - mean) * rstd * gw + gb;
    v = v / (1.0f + __expf(-v));
    v = v * mw[g * 32 + j];
    v = v / (1.0f + __expf(-v));
    p[j] = v;
  }
}

extern "C" void kernel_launch(void* const* d_in, const int* in_sizes, int n_in,
                              void* d_out, int out_size, void* d_ws, size_t ws_size,
                              hipStream_t stream) {
  const float* x    = (const float*)d_in[0];
  const float* wgt  = (const float*)d_in[1];
  const float* bias = (const float*)d_in[2];
  const float* gnw  = (const float*)d_in[3];
  const float* gnb  = (const float*)d_in[4];
  const float* mwp  = (const float*)d_in[5];
  float* out = (float*)d_out;

  size_t need = ((size_t)MM * KK + (size_t)NN * KK) * 2;
  if (ws_size >= need) {
    uint16_t* xbf = (uint16_t*)d_ws;
    uint16_t* wbf = xbf + (size_t)MM * KK;
    cvt_f32_to_bf16<<<2048, 256, 0, stream>>>(x, xbf, (MM * KK) / 4);
    cvt_f32_to_bf16<<<512, 256, 0, stream>>>(wgt, wbf, (NN * KK) / 4);
    (void)hipFuncSetAttribute((const void*)gemm_gn_silu_ol,
                              hipFuncAttributeMaxDynamicSharedMemorySize, 131072);
    gemm_gn_silu_ol<<<512, 512, 131072, stream>>>(xbf, wbf, bias, gnw, gnb, mwp, out);
  } else {
    naive_gemm<<<(MM * (size_t)NN) / 256, 256, 0, stream>>>(x, wgt, bias, out);
    naive_post<<<(MM * GG) / 256, 256, 0, stream>>>(out, gnw, gnb, mwp);
  }
}